// Round 1
// baseline (17.062 us; speedup 1.0000x reference)
//
#include <hip/hip_runtime.h>
#include <math.h>

// Problem constants (from reference)
#define O_NUM 256
#define IN_NUM 768
#define NS 32            // B*R = 8*4 samples
#define L0 128
#define L1 22
#define L2 4
// Padded LDS row strides (odd -> conflict-free for sample-strided access)
#define Y0S 133          // >= L1*6 = 132
#define Y1S 25           // >= L2*6 = 24
#define Y2S 7            // >= 1*6  = 6

// 6-level binary-tree LUT mux: w[64] (soft LUT), b[6] (soft bits, LSB first).
// y = (1-b)*y[...,0] + b*y[...,1] per level == lerp.
__device__ __forceinline__ float lut6(const float* __restrict__ w, const float b[6]) {
    float v[32];
#pragma unroll
    for (int j = 0; j < 32; ++j)
        v[j] = fmaf(b[0], w[2 * j + 1] - w[2 * j], w[2 * j]);
#pragma unroll
    for (int lvl = 1; lvl < 6; ++lvl) {
        const int n = 32 >> lvl;
#pragma unroll
        for (int j = 0; j < n; ++j)
            v[j] = fmaf(b[lvl], v[2 * j + 1] - v[2 * j], v[2 * j]);
    }
    return v[0];
}

__global__ __launch_bounds__(512) void lut_quant_fc_kernel(
    const float* __restrict__ x,    // [NS][IN_NUM]
    const float* __restrict__ w0,   // [O_NUM][L0][64]
    const float* __restrict__ w1,   // [O_NUM][L1][64]
    const float* __restrict__ w2,   // [O_NUM][L2][64]
    const float* __restrict__ w3,   // [O_NUM][1][64]
    float* __restrict__ out)        // [NS][O_NUM]
{
    const int o = blockIdx.x;
    const int tid = threadIdx.x;

    __shared__ float wq0[L0 * 64];   // 32 KB
    __shared__ float wq1[L1 * 64];   // 5.5 KB
    __shared__ float wq2[L2 * 64];   // 1 KB
    __shared__ float wq3[64];
    __shared__ float y0[NS * Y0S];   // ~16.6 KB
    __shared__ float y1[NS * Y1S];   // ~3.1 KB
    __shared__ float y2[NS * Y2S];   // ~0.9 KB

    // ---- Phase A: weight transform (tanh(w)+1)/2 for this o, into LDS ----
    {
        const float* gw0 = w0 + (size_t)o * (L0 * 64);
        for (int i = tid; i < L0 * 64; i += 512) wq0[i] = 0.5f * tanhf(gw0[i]) + 0.5f;
        const float* gw1 = w1 + (size_t)o * (L1 * 64);
        for (int i = tid; i < L1 * 64; i += 512) wq1[i] = 0.5f * tanhf(gw1[i]) + 0.5f;
        const float* gw2 = w2 + (size_t)o * (L2 * 64);
        if (tid < L2 * 64) wq2[tid] = 0.5f * tanhf(gw2[tid]) + 0.5f;
        const float* gw3 = w3 + (size_t)o * 64;
        if (tid < 64) wq3[tid] = 0.5f * tanhf(gw3[tid]) + 0.5f;
        // zero the pad bit-slots consumed by the next layer (pad bit = 0 picks branch 0)
        if (tid < NS * 4) {                      // y0 cols 128..131
            int s = tid >> 2; int c = L0 + (tid & 3);
            y0[s * Y0S + c] = 0.0f;
        }
        if (tid >= 128 && tid < 128 + NS * 2) {  // y1 cols 22..23
            int t = tid - 128; int s = t >> 1;
            y1[s * Y1S + L1 + (t & 1)] = 0.0f;
        }
        if (tid >= 256 && tid < 256 + NS * 2) {  // y2 cols 4..5
            int t = tid - 256; int s = t >> 1;
            y2[s * Y2S + L2 + (t & 1)] = 0.0f;
        }
    }
    __syncthreads();

    // ---- Phase B: layer 0 — 32 samples x 128 cells = 4096 tasks ----
    // sample-fast mapping: half-wave shares a cell -> LDS weight reads broadcast
    for (int t = tid; t < NS * L0; t += 512) {
        const int s = t & 31;
        const int l = t >> 5;
        const float* xb = x + s * IN_NUM + l * 6;
        float b[6];
#pragma unroll
        for (int j = 0; j < 6; ++j) b[j] = xb[j];
        y0[s * Y0S + l] = lut6(&wq0[l * 64], b);
    }
    __syncthreads();

    // ---- Phase C: layer 1 — 32 x 22 = 704 tasks ----
    for (int t = tid; t < NS * L1; t += 512) {
        const int s = t & 31;
        const int l = t >> 5;
        const float* xb = &y0[s * Y0S + l * 6];
        float b[6];
#pragma unroll
        for (int j = 0; j < 6; ++j) b[j] = xb[j];
        y1[s * Y1S + l] = lut6(&wq1[l * 64], b);
    }
    __syncthreads();

    // ---- Phase D: layer 2 — 32 x 4 = 128 tasks ----
    if (tid < NS * L2) {
        const int s = tid & 31;
        const int l = tid >> 5;
        const float* xb = &y1[s * Y1S + l * 6];
        float b[6];
#pragma unroll
        for (int j = 0; j < 6; ++j) b[j] = xb[j];
        y2[s * Y2S + l] = lut6(&wq2[l * 64], b);
    }
    __syncthreads();

    // ---- Phase E: layer 3 — 32 tasks, write out ----
    if (tid < NS) {
        const int s = tid;
        const float* xb = &y2[s * Y2S];
        float b[6];
#pragma unroll
        for (int j = 0; j < 6; ++j) b[j] = xb[j];
        out[s * O_NUM + o] = lut6(wq3, b);
    }
}

extern "C" void kernel_launch(void* const* d_in, const int* in_sizes, int n_in,
                              void* d_out, int out_size, void* d_ws, size_t ws_size,
                              hipStream_t stream) {
    const float* x  = (const float*)d_in[0];
    const float* w0 = (const float*)d_in[1];
    const float* w1 = (const float*)d_in[2];
    const float* w2 = (const float*)d_in[3];
    const float* w3 = (const float*)d_in[4];
    float* out = (float*)d_out;

    lut_quant_fc_kernel<<<dim3(O_NUM), dim3(512), 0, stream>>>(x, w0, w1, w2, w3, out);
}

// Round 2
// 15.086 us; speedup vs baseline: 1.1310x; 1.1310x over previous
//
#include <hip/hip_runtime.h>

// Problem constants (from reference)
#define O_NUM 256
#define IN_NUM 768
#define NS 32            // B*R = 8*4 samples
#define L0 128
#define L1 22
#define L2 4
// Padded LDS row strides (odd -> conflict-free for sample-strided access)
#define Y0S 133          // >= L1*6 = 132
#define Y1S 25           // >= L2*6 = 24

// (tanh(w)+1)/2 == sigmoid(2w) == 1/(1 + 2^(-2*log2(e)*w))
__device__ __forceinline__ float fast_sig2(float w) {
    float e = __builtin_amdgcn_exp2f(w * -2.8853900817779268f);
    return __builtin_amdgcn_rcpf(1.0f + e);
}

// 6-level binary-tree LUT mux over a register-resident row w[64].
__device__ __forceinline__ float lut6(const float* __restrict__ w, const float* __restrict__ b) {
    float v[32];
#pragma unroll
    for (int j = 0; j < 32; ++j)
        v[j] = fmaf(b[0], w[2 * j + 1] - w[2 * j], w[2 * j]);
#pragma unroll
    for (int lvl = 1; lvl < 6; ++lvl) {
        const int n = 32 >> lvl;
#pragma unroll
        for (int j = 0; j < n; ++j)
            v[j] = fmaf(b[lvl], v[2 * j + 1] - v[2 * j], v[2 * j]);
    }
    return v[0];
}

// Load a 64-float LUT row from LDS via ds_read_b128 into registers.
__device__ __forceinline__ void load_row_lds(float* __restrict__ w, const float* __restrict__ src) {
    const float4* p = (const float4*)src;   // rows are 256B-aligned
#pragma unroll
    for (int k = 0; k < 16; ++k) {
        float4 q = p[k];
        w[4 * k + 0] = q.x; w[4 * k + 1] = q.y; w[4 * k + 2] = q.z; w[4 * k + 3] = q.w;
    }
}

__global__ __launch_bounds__(512) void lut_quant_fc_kernel(
    const float* __restrict__ x,    // [NS][IN_NUM]
    const float* __restrict__ w0,   // [O_NUM][L0][64]
    const float* __restrict__ w1,   // [O_NUM][L1][64]
    const float* __restrict__ w2,   // [O_NUM][L2][64]
    const float* __restrict__ w3,   // [O_NUM][1][64]
    float* __restrict__ out)        // [NS][O_NUM]
{
    const int o = blockIdx.x;
    const int tid = threadIdx.x;

    __shared__ float wq1[L1 * 64];   // 5.5 KB
    __shared__ float wq2[L2 * 64];   // 1 KB
    __shared__ float wq3[64];
    __shared__ float y0[NS * Y0S];   // ~16.6 KB
    __shared__ float y1[NS * Y1S];   // ~3.1 KB

    // ---- Layer 0 (no barrier needed before it): cell-fixed mapping ----
    // thread -> (cell l, sample-group sg of 8 samples); w0 row lives in VGPRs.
    const int l  = tid >> 2;        // 0..127
    const int sg = tid & 3;         // 0..3

    float rw[64];
    {
        const float4* g = (const float4*)(w0 + ((size_t)o * L0 + l) * 64);
#pragma unroll
        for (int k = 0; k < 16; ++k) {
            float4 q = g[k];
            rw[4 * k + 0] = fast_sig2(q.x);
            rw[4 * k + 1] = fast_sig2(q.y);
            rw[4 * k + 2] = fast_sig2(q.z);
            rw[4 * k + 3] = fast_sig2(q.w);
        }
    }

    // ---- Setup: transform w1/w2/w3 into LDS; zero pad slots ----
    if (tid < 352) {                                   // wq1: 352 float4
        float4 q = ((const float4*)(w1 + (size_t)o * (L1 * 64)))[tid];
        float4 r = { fast_sig2(q.x), fast_sig2(q.y), fast_sig2(q.z), fast_sig2(q.w) };
        ((float4*)wq1)[tid] = r;
    } else if (tid < 416) {                            // wq2: 64 float4
        int i = tid - 352;
        float4 q = ((const float4*)(w2 + (size_t)o * (L2 * 64)))[i];
        float4 r = { fast_sig2(q.x), fast_sig2(q.y), fast_sig2(q.z), fast_sig2(q.w) };
        ((float4*)wq2)[i] = r;
    } else if (tid < 432) {                            // wq3: 16 float4
        int i = tid - 416;
        float4 q = ((const float4*)(w3 + (size_t)o * 64))[i];
        float4 r = { fast_sig2(q.x), fast_sig2(q.y), fast_sig2(q.z), fast_sig2(q.w) };
        ((float4*)wq3)[i] = r;
    }
    if (tid < NS * 4) {                                // y0 pad cols 128..131 = 0
        int s = tid >> 2; int c = L0 + (tid & 3);
        y0[s * Y0S + c] = 0.0f;
    }
    if (tid < NS * 2) {                                // y1 pad cols 22..23 = 0
        int s = tid >> 1;
        y1[s * Y1S + L1 + (tid & 1)] = 0.0f;
    }

    // ---- Layer 0 main: 8 samples per thread, weights in registers ----
#pragma unroll 2
    for (int i = 0; i < 8; ++i) {
        const int s = sg * 8 + i;
        const float2* xb = (const float2*)(x + (size_t)s * IN_NUM + l * 6);  // 8B-aligned
        float2 b01 = xb[0], b23 = xb[1], b45 = xb[2];
        float b[6] = { b01.x, b01.y, b23.x, b23.y, b45.x, b45.y };
        y0[s * Y0S + l] = lut6(rw, b);
    }
    __syncthreads();

    // ---- Layer 1: 32 x 22 = 704 tasks, sample-fast (weight rows broadcast) ----
    for (int t = tid; t < NS * L1; t += 512) {
        const int s = t & 31;
        const int c = t >> 5;
        float w[64];
        load_row_lds(w, &wq1[c * 64]);
        float b[6];
#pragma unroll
        for (int j = 0; j < 6; ++j) b[j] = y0[s * Y0S + c * 6 + j];
        y1[s * Y1S + c] = lut6(w, b);
    }
    __syncthreads();

    // ---- Layers 2+3 fused: one thread per sample ----
    if (tid < NS) {
        const int s = tid;
        float bits[24];
#pragma unroll
        for (int j = 0; j < 24; ++j) bits[j] = y1[s * Y1S + j];
        float c[6];
#pragma unroll
        for (int l2 = 0; l2 < 4; ++l2) {
            float w[64];
            load_row_lds(w, &wq2[l2 * 64]);
            c[l2] = lut6(w, &bits[l2 * 6]);
        }
        c[4] = 0.0f; c[5] = 0.0f;
        float w[64];
        load_row_lds(w, wq3);
        out[(size_t)s * O_NUM + o] = lut6(w, c);
    }
}

extern "C" void kernel_launch(void* const* d_in, const int* in_sizes, int n_in,
                              void* d_out, int out_size, void* d_ws, size_t ws_size,
                              hipStream_t stream) {
    const float* x  = (const float*)d_in[0];
    const float* w0 = (const float*)d_in[1];
    const float* w1 = (const float*)d_in[2];
    const float* w2 = (const float*)d_in[3];
    const float* w3 = (const float*)d_in[4];
    float* out = (float*)d_out;

    lut_quant_fc_kernel<<<dim3(O_NUM), dim3(512), 0, stream>>>(x, w0, w1, w2, w3, out);
}